// Round 4
// baseline (206.809 us; speedup 1.0000x reference)
//
#include <hip/hip_runtime.h>

#define HH 256
#define WW 256
#define HWPX 65536
#define BB 8
#define KK 21
#define CC 32
#define NT 8192                 // affinity blocks
#define E_LOG2E 1.4426950408889634f

typedef _Float16 half2v __attribute__((ext_vector_type(2)));
typedef _Float16 half8  __attribute__((ext_vector_type(8)));
typedef float    f32x4v __attribute__((ext_vector_type(4)));
union F4H { float4 f4; half2v h[4]; half8 h8; };

// ---------------- kernel 1: T + |q|^2 + planar f16 pack, 1 px/thread (round-1 verbatim) ----------------
// Planar layout doubles as the MFMA fragment layout: plane g holds channels 8g..8g+7 as one
// float4 per pixel -> lane (g=lane>>4) loads its 8-channel k-chunk with a single dwordx4.
__global__ __launch_bounds__(256) void prep(const float* __restrict__ cls,
                                            const float* __restrict__ feat,
                                            float4* __restrict__ fpk,
                                            float2* __restrict__ TN) {
    const int tid = blockIdx.x * 256 + threadIdx.x;   // 0..524287 (b*HWPX+p)
    const int b = tid >> 16;
    const int p = tid & (HWPX - 1);

    const float* cbase = cls + (size_t)b * KK * HWPX + p;
    float T = 0.f;
#pragma unroll
    for (int k = 0; k < KK; ++k) T += cbase[(size_t)k * HWPX];

    const float* src = feat + (size_t)b * CC * HWPX + p;
    float nq = 0.f;
#pragma unroll
    for (int j = 0; j < 4; ++j) {
        F4H u;
#pragma unroll
        for (int k = 0; k < 4; ++k) {
            float a  = src[(size_t)(j * 8 + 2 * k) * HWPX];
            float b2 = src[(size_t)(j * 8 + 2 * k + 1) * HWPX];
            u.h[k] = __builtin_bit_cast(half2v, __builtin_amdgcn_cvt_pkrtz(a, b2));
            nq = __builtin_amdgcn_fdot2(u.h[k], u.h[k], nq, false);
        }
        fpk[(size_t)j * (BB * HWPX) + tid] = u.f4;
    }
    TN[tid] = make_float2(T, nq);
}

// ---------------- kernel 2 (hot): MFMA affinity + fused per-(b,j) reduction ----------------
// Wave = 16-px row tile (y, x0..x0+15). A-frag = 16px x 32ch. Per neighbor row ny (dy -4..4):
// two disjoint B windows [x0-4..x0+11], [x0+12..x0+27] cover all |dx|<=4 pairs exactly once
// -> 2x mfma_f32_16x16x32_f16 produce all 512 dot products (144 useful after circle mask).
// C layout: col=lane&15 (neighbor px), row=4*(lane>>4)+reg (own px). Exponent assembled in
// log2-domain: e2 = 2E*dot - E*(dy^2+dx^2)/16 - E*np - E*nq; w = exp2(e2), masked by circle
// + x-bounds (OOB lanes get swr=999). deg/V accumulate per (lane,reg); col-sum via shfl_xor
// butterfly; cls-fused reduce maps j = (lane&15) [+16]; per-block partials (no atomics).
__global__ __launch_bounds__(256) void affinity_mfma(const float4* __restrict__ fpk,
                                                     const float2* __restrict__ TN,
                                                     const float* __restrict__ cls,
                                                     float* __restrict__ partial) {
    __shared__ float smN[4][21], smD[4][21];
    const int L    = blockIdx.x;        // 0..8191 ; L%8 = batch (XCD swizzle: fpk slice L2-resident)
    const int b    = L & 7;
    const int t    = L >> 3;            // 0..1023
    const int xt   = t >> 6;            // 0..15
    const int ygrp = t & 63;            // 0..63
    const int wid  = threadIdx.x >> 6;
    const int lane = threadIdx.x & 63;
    const int g    = lane >> 4;         // k-chunk = feature plane
    const int c    = lane & 15;         // fragment col
    const int y    = ygrp * 4 + wid;    // this wave's row
    const int x0   = xt * 16;

    const size_t bofs = (size_t)b * HWPX;
    const float4* fb  = fpk + bofs;
    const float2* tnb = TN + bofs;

    // A fragment: pixel x0+c, channels 8g..8g+7
    const int rowp = (y << 8) + x0;
    F4H afr; afr.f4 = fb[(size_t)g * (BB * HWPX) + rowp + c];

    // np (scaled by log2e) for my 4 C-rows: pixels x0 + 4g + r
    float npE[4];
#pragma unroll
    for (int r = 0; r < 4; ++r) npE[r] = tnb[rowp + 4 * g + r].y * E_LOG2E;

    // static per (window,reg): dx^2 (999 if B col out of image) and cst = -E/16*dx^2 - E*np
    int   swr[2][4];
    float cst[2][4];
#pragma unroll
    for (int w = 0; w < 2; ++w) {
        const int w0  = w ? 12 : -4;
        const int xbu = x0 + w0 + c;
        const bool inb = (unsigned)xbu < WW;
#pragma unroll
        for (int r = 0; r < 4; ++r) {
            const int dx = w0 + c - 4 * g - r;
            swr[w][r] = inb ? dx * dx : 999;
            cst[w][r] = fmaf((float)(dx * dx), -E_LOG2E / 16.f, -npE[r]);
        }
    }

    float pdeg[4] = {0.f, 0.f, 0.f, 0.f};
    float pV[4]   = {0.f, 0.f, 0.f, 0.f};

#pragma unroll 1
    for (int dyi = 0; dyi < 9; ++dyi) {
        const int ny = y + dyi - 4;                 // uniform per wave
        if ((unsigned)ny >= HH) continue;
        const int dy2  = (dyi - 4) * (dyi - 4);
        const float cdy = (float)dy2 * (-E_LOG2E / 16.f);
        const int thr  = 25 - dy2;
        const int nrow = ny << 8;

#pragma unroll
        for (int w = 0; w < 2; ++w) {
            const int w0  = w ? 12 : -4;
            const int xbc = min(max(x0 + w0 + c, 0), WW - 1);
            const int q   = nrow + xbc;

            F4H bfr; bfr.f4 = fb[(size_t)g * (BB * HWPX) + q];
            const float2 tq = tnb[q];

            f32x4v cz = {0.f, 0.f, 0.f, 0.f};
            cz = __builtin_amdgcn_mfma_f32_16x16x32_f16(afr.h8, bfr.h8, cz, 0, 0, 0);

            const float t1 = fmaf(tq.y, -E_LOG2E, cdy);
#pragma unroll
            for (int r = 0; r < 4; ++r) {
                const float e2 = fmaf(cz[r], 2.f * E_LOG2E, cst[w][r] + t1);
                float wv = __builtin_exp2f(e2);
                wv = (swr[w][r] < thr) ? wv : 0.f;   // circle + x-bounds mask
                pdeg[r] += wv;
                pV[r]   = fmaf(wv, tq.x, pV[r]);
            }
        }
    }

    // col-sum over the 16 neighbor cols (butterfly within 16-lane group)
#pragma unroll
    for (int m = 1; m <= 8; m <<= 1) {
#pragma unroll
        for (int r = 0; r < 4; ++r) {
            pdeg[r] += __shfl_xor(pdeg[r], m, 64);
            pV[r]   += __shfl_xor(pV[r], m, 64);
        }
    }
    // lane (g,c) now holds deg/V for pixels x0+4g+r (replicated over c)

    // fused cls reduce: lane c handles j=c (and j=c+16 for c<5) over its 4 pixels
    float n0 = 0.f, d0 = 0.f, n1 = 0.f, d1 = 0.f;
    const float* clsb = cls + (size_t)b * KK * HWPX + rowp + 4 * g;
#pragma unroll
    for (int r = 0; r < 4; ++r) {
        const float s0 = clsb[(size_t)c * HWPX + r];
        n0 = fmaf(s0, pV[r], n0);
        d0 = fmaf(s0, pdeg[r], d0);
        if (c < 5) {
            const float s1 = clsb[(size_t)(c + 16) * HWPX + r];
            n1 = fmaf(s1, pV[r], n1);
            d1 = fmaf(s1, pdeg[r], d1);
        }
    }
    // sum over the 4 lane-groups g
#pragma unroll
    for (int m = 16; m <= 32; m <<= 1) {
        n0 += __shfl_xor(n0, m, 64);
        d0 += __shfl_xor(d0, m, 64);
        n1 += __shfl_xor(n1, m, 64);
        d1 += __shfl_xor(d1, m, 64);
    }
    if (lane < 16) {
        smN[wid][lane] = n0;
        smD[wid][lane] = d0;
        if (lane < 5) { smN[wid][16 + lane] = n1; smD[wid][16 + lane] = d1; }
    }
    __syncthreads();
    if (threadIdx.x < 2 * KK) {                      // 42 partial slots per block, no atomics
        const int jq = threadIdx.x;
        const float v = (jq < KK)
            ? (smN[0][jq] + smN[1][jq] + smN[2][jq] + smN[3][jq])
            : (smD[0][jq - KK] + smD[1][jq - KK] + smD[2][jq - KK] + smD[3][jq - KK]);
        partial[(size_t)jq * NT + (size_t)b * 1024 + t] = v;
    }
}

// ---------------- kernel 3: sum per-block partials -> numer/denom[b][j] ----------------
__global__ __launch_bounds__(256) void reduce_part(const float* __restrict__ partial,
                                                   float* __restrict__ numer,
                                                   float* __restrict__ denom) {
    __shared__ float sm[4];
    const int jq = blockIdx.x;   // 0..41
    const int b  = blockIdx.y;   // 0..7
    const float* src = partial + (size_t)jq * NT + (size_t)b * 1024;
    float a = src[threadIdx.x] + src[threadIdx.x + 256]
            + src[threadIdx.x + 512] + src[threadIdx.x + 768];
#pragma unroll
    for (int off = 32; off > 0; off >>= 1) a += __shfl_down(a, off);
    if ((threadIdx.x & 63) == 0) sm[threadIdx.x >> 6] = a;
    __syncthreads();
    if (threadIdx.x == 0) {
        const float v = sm[0] + sm[1] + sm[2] + sm[3];
        if (jq < KK) numer[b * KK + jq] = v;
        else         denom[b * KK + jq - KK] = v;
    }
}

// ---------------- kernel 4: out = sum_{b,j} numer/denom ----------------
__global__ __launch_bounds__(256) void finalize(const float* __restrict__ numer,
                                                const float* __restrict__ denom,
                                                float* __restrict__ out) {
    __shared__ float sm[4];
    int i = threadIdx.x;
    float r = 0.f;
    if (i < BB * KK) r = numer[i] / denom[i];
#pragma unroll
    for (int off = 32; off > 0; off >>= 1) r += __shfl_down(r, off);
    if ((i & 63) == 0) sm[i >> 6] = r;
    __syncthreads();
    if (i == 0) out[0] = sm[0] + sm[1] + sm[2] + sm[3];
}

extern "C" void kernel_launch(void* const* d_in, const int* in_sizes, int n_in,
                              void* d_out, int out_size, void* d_ws, size_t ws_size,
                              hipStream_t stream) {
    const float* cls  = (const float*)d_in[0];  // [B,K,H,W]
    const float* feat = (const float*)d_in[1];  // [B,C,H,W]
    float* out = (float*)d_out;

    const size_t BHW = (size_t)BB * HWPX;
    // fpk (33.5 MB) | TN (4.2 MB) | partial (1.4 MB) | numer | denom   (~39 MB)
    float4* fpk     = (float4*)d_ws;
    float2* TN      = (float2*)((char*)d_ws + BHW * 64);
    float*  partial = (float*)((char*)TN + BHW * 8);
    float*  numer   = partial + (size_t)2 * KK * NT;
    float*  denom   = numer + BB * KK;

    prep<<<dim3((BB * HWPX) / 256), dim3(256), 0, stream>>>(cls, feat, fpk, TN);
    affinity_mfma<<<dim3(NT), dim3(256), 0, stream>>>(fpk, TN, cls, partial);
    reduce_part<<<dim3(2 * KK, BB), dim3(256), 0, stream>>>(partial, numer, denom);
    finalize<<<dim3(1), dim3(256), 0, stream>>>(numer, denom, out);
}

// Round 5
// 199.819 us; speedup vs baseline: 1.0350x; 1.0350x over previous
//
#include <hip/hip_runtime.h>

#define HH 256
#define WW 256
#define HWPX 65536
#define BB 8
#define KK 21
#define CC 32
#define NT 8192                 // affinity blocks
#define E_LOG2E 1.4426950408889634f
#define PEN -30000.0f           // exp2(PEN + bounded dot) flushes to exactly +0

typedef _Float16 half2v __attribute__((ext_vector_type(2)));
typedef _Float16 half8  __attribute__((ext_vector_type(8)));
typedef float    f32x4v __attribute__((ext_vector_type(4)));
union F4H { float4 f4; half2v h[4]; half8 h8; };

// ---------------- kernel 1: T + |q|^2 + planar f16 pack, 1 px/thread (verbatim, known-good) ----------------
__global__ __launch_bounds__(256) void prep(const float* __restrict__ cls,
                                            const float* __restrict__ feat,
                                            float4* __restrict__ fpk,
                                            float2* __restrict__ TN) {
    const int tid = blockIdx.x * 256 + threadIdx.x;   // 0..524287 (b*HWPX+p)
    const int b = tid >> 16;
    const int p = tid & (HWPX - 1);

    const float* cbase = cls + (size_t)b * KK * HWPX + p;
    float T = 0.f;
#pragma unroll
    for (int k = 0; k < KK; ++k) T += cbase[(size_t)k * HWPX];

    const float* src = feat + (size_t)b * CC * HWPX + p;
    float nq = 0.f;
#pragma unroll
    for (int j = 0; j < 4; ++j) {
        F4H u;
#pragma unroll
        for (int k = 0; k < 4; ++k) {
            float a  = src[(size_t)(j * 8 + 2 * k) * HWPX];
            float b2 = src[(size_t)(j * 8 + 2 * k + 1) * HWPX];
            u.h[k] = __builtin_bit_cast(half2v, __builtin_amdgcn_cvt_pkrtz(a, b2));
            nq = __builtin_amdgcn_fdot2(u.h[k], u.h[k], nq, false);
        }
        fpk[(size_t)j * (BB * HWPX) + tid] = u.f4;
    }
    TN[tid] = make_float2(T, nq);
}

// ---------------- kernel 2 (hot): MFMA affinity, static-masked postlude ----------------
// Same verified tiling as round 4 (wave = 16-px row seg; 2 B-windows/dyi; C: col=lane&15,
// row=4*(lane>>4)+reg). Changes, all targeting VALU issue count (round-4: 88.6% VALUBusy):
//  - circle/x-bounds mask folded into 3 STATIC cst arrays (dy2<=4 / dy2==9 / dy2==16):
//    invalid lanes carry PEN so exp2 flushes to +0 -> cmp+cndmask deleted (postlude 7->5/reg)
//  - dyi loop split into 3 static groups so cst indexing is compile-time (no scratch)
//  - loads: uniform SGPR base (batch + ny row) + loop-invariant VGPR byte offset -> 0 addr VALU
//  - hoisted zero C-input (no per-MFMA re-zeroing)
__global__ __launch_bounds__(256) void affinity_mfma(const float4* __restrict__ fpk,
                                                     const float2* __restrict__ TN,
                                                     const float* __restrict__ cls,
                                                     float* __restrict__ partial) {
    __shared__ float smN[4][21], smD[4][21];
    const int L    = blockIdx.x;        // 0..8191 ; L%8 = batch (XCD swizzle)
    const int b    = L & 7;
    const int t    = L >> 3;            // 0..1023
    const int xt   = t >> 6;            // 0..15
    const int ygrp = t & 63;            // 0..63
    const int wid  = threadIdx.x >> 6;
    const int lane = threadIdx.x & 63;
    const int g    = lane >> 4;         // k-chunk = feature plane
    const int c    = lane & 15;         // fragment col
    const int y    = ygrp * 4 + wid;    // this wave's row
    const int x0   = xt * 16;

    const size_t bofs = (size_t)b * HWPX;
    const float4* fb  = fpk + bofs;
    const float2* tnb = TN + bofs;

    // A fragment: pixel x0+c, channels 8g..8g+7
    const int rowp = (y << 8) + x0;
    F4H afr; afr.f4 = fb[(size_t)g * (BB * HWPX) + rowp + c];

    float npE[4];
#pragma unroll
    for (int r = 0; r < 4; ++r) npE[r] = tnb[rowp + 4 * g + r].y * E_LOG2E;

    // static per (window,reg): cst = -E/16*dx^2 - E*np, or PEN when (x OOB | dx^2 > limit)
    // three validity sets: A: dy2<=4 -> dx2<=16 ; B: dy2==9 -> dx2<=9 ; C: dy2==16 -> dx2<=4
    float cstA[2][4], cstB[2][4], cstC[2][4];
    int   voffF[2], voffT[2];           // loop-invariant per-lane byte offsets
#pragma unroll
    for (int w = 0; w < 2; ++w) {
        const int w0  = w ? 12 : -4;
        const int xbu = x0 + w0 + c;
        const bool inb = (unsigned)xbu < WW;
        const int xbc = min(max(xbu, 0), WW - 1);
        voffF[w] = (g * (BB * HWPX) + xbc) * 16;
        voffT[w] = xbc * 8;
#pragma unroll
        for (int r = 0; r < 4; ++r) {
            const int dx = w0 + c - 4 * g - r;
            const int s2 = dx * dx;
            const float bp = fmaf((float)s2, -E_LOG2E / 16.f, -npE[r]);
            cstA[w][r] = (inb && s2 <= 16) ? bp : PEN;
            cstB[w][r] = (inb && s2 <= 9)  ? bp : PEN;
            cstC[w][r] = (inb && s2 <= 4)  ? bp : PEN;
        }
    }

    const f32x4v czero = {0.f, 0.f, 0.f, 0.f};
    float pdeg[4] = {0.f, 0.f, 0.f, 0.f};
    float pV[4]   = {0.f, 0.f, 0.f, 0.f};

    // uniform scalar bases: batch start in bytes; per-body add ny*rowstride
    const char* fpkB = (const char*)fpk + bofs * 16;   // plane-0, batch b
    const char* tnB  = (const char*)TN + bofs * 8;

    auto body = [&](const float (&cst)[2][4], int ny, float cdy) {
        if ((unsigned)ny >= HH) return;                // uniform: OOB row contributes 0
        const char* pF = fpkB + ((size_t)ny << 12);    // ny*256px*16B (SGPR-uniform)
        const char* pT = tnB  + ((size_t)ny << 11);    // ny*256px*8B
#pragma unroll
        for (int w = 0; w < 2; ++w) {
            F4H bfr; bfr.f4 = *(const float4*)(pF + voffF[w]);
            const float2 tq = *(const float2*)(pT + voffT[w]);
            f32x4v cz = __builtin_amdgcn_mfma_f32_16x16x32_f16(afr.h8, bfr.h8, czero, 0, 0, 0);
            const float t1 = fmaf(tq.y, -E_LOG2E, cdy);
#pragma unroll
            for (int r = 0; r < 4; ++r) {
                const float e2 = fmaf(cz[r], 2.f * E_LOG2E, cst[w][r] + t1);
                const float wv = __builtin_exp2f(e2);  // masked lanes: PEN -> +0 exactly
                pdeg[r] += wv;
                pV[r]   = fmaf(wv, tq.x, pV[r]);
            }
        }
    };

    // group A: |dy| <= 2 (runtime loop, static cst identity)
#pragma unroll 1
    for (int d = -2; d <= 2; ++d)
        body(cstA, y + d, (float)(d * d) * (-E_LOG2E / 16.f));
    // group B: |dy| == 3
    body(cstB, y - 3, 9.f  * (-E_LOG2E / 16.f));
    body(cstB, y + 3, 9.f  * (-E_LOG2E / 16.f));
    // group C: |dy| == 4
    body(cstC, y - 4, 16.f * (-E_LOG2E / 16.f));
    body(cstC, y + 4, 16.f * (-E_LOG2E / 16.f));

    // col-sum over the 16 neighbor cols (butterfly within 16-lane group)
#pragma unroll
    for (int m = 1; m <= 8; m <<= 1) {
#pragma unroll
        for (int r = 0; r < 4; ++r) {
            pdeg[r] += __shfl_xor(pdeg[r], m, 64);
            pV[r]   += __shfl_xor(pV[r], m, 64);
        }
    }

    // fused cls reduce: lane c handles j=c (and j=c+16 for c<5) over its 4 pixels
    float n0 = 0.f, d0 = 0.f, n1 = 0.f, d1 = 0.f;
    const float* clsb = cls + (size_t)b * KK * HWPX + rowp + 4 * g;
#pragma unroll
    for (int r = 0; r < 4; ++r) {
        const float s0 = clsb[(size_t)c * HWPX + r];
        n0 = fmaf(s0, pV[r], n0);
        d0 = fmaf(s0, pdeg[r], d0);
        if (c < 5) {
            const float s1 = clsb[(size_t)(c + 16) * HWPX + r];
            n1 = fmaf(s1, pV[r], n1);
            d1 = fmaf(s1, pdeg[r], d1);
        }
    }
#pragma unroll
    for (int m = 16; m <= 32; m <<= 1) {
        n0 += __shfl_xor(n0, m, 64);
        d0 += __shfl_xor(d0, m, 64);
        n1 += __shfl_xor(n1, m, 64);
        d1 += __shfl_xor(d1, m, 64);
    }
    if (lane < 16) {
        smN[wid][lane] = n0;
        smD[wid][lane] = d0;
        if (lane < 5) { smN[wid][16 + lane] = n1; smD[wid][16 + lane] = d1; }
    }
    __syncthreads();
    if (threadIdx.x < 2 * KK) {                      // 42 partial slots per block, no atomics
        const int jq = threadIdx.x;
        const float v = (jq < KK)
            ? (smN[0][jq] + smN[1][jq] + smN[2][jq] + smN[3][jq])
            : (smD[0][jq - KK] + smD[1][jq - KK] + smD[2][jq - KK] + smD[3][jq - KK]);
        partial[(size_t)jq * NT + (size_t)b * 1024 + t] = v;
    }
}

// ---------------- kernel 3: sum per-block partials -> numer/denom[b][j] ----------------
__global__ __launch_bounds__(256) void reduce_part(const float* __restrict__ partial,
                                                   float* __restrict__ numer,
                                                   float* __restrict__ denom) {
    __shared__ float sm[4];
    const int jq = blockIdx.x;   // 0..41
    const int b  = blockIdx.y;   // 0..7
    const float* src = partial + (size_t)jq * NT + (size_t)b * 1024;
    float a = src[threadIdx.x] + src[threadIdx.x + 256]
            + src[threadIdx.x + 512] + src[threadIdx.x + 768];
#pragma unroll
    for (int off = 32; off > 0; off >>= 1) a += __shfl_down(a, off);
    if ((threadIdx.x & 63) == 0) sm[threadIdx.x >> 6] = a;
    __syncthreads();
    if (threadIdx.x == 0) {
        const float v = sm[0] + sm[1] + sm[2] + sm[3];
        if (jq < KK) numer[b * KK + jq] = v;
        else         denom[b * KK + jq - KK] = v;
    }
}

// ---------------- kernel 4: out = sum_{b,j} numer/denom ----------------
__global__ __launch_bounds__(256) void finalize(const float* __restrict__ numer,
                                                const float* __restrict__ denom,
                                                float* __restrict__ out) {
    __shared__ float sm[4];
    int i = threadIdx.x;
    float r = 0.f;
    if (i < BB * KK) r = numer[i] / denom[i];
#pragma unroll
    for (int off = 32; off > 0; off >>= 1) r += __shfl_down(r, off);
    if ((i & 63) == 0) sm[i >> 6] = r;
    __syncthreads();
    if (i == 0) out[0] = sm[0] + sm[1] + sm[2] + sm[3];
}

extern "C" void kernel_launch(void* const* d_in, const int* in_sizes, int n_in,
                              void* d_out, int out_size, void* d_ws, size_t ws_size,
                              hipStream_t stream) {
    const float* cls  = (const float*)d_in[0];  // [B,K,H,W]
    const float* feat = (const float*)d_in[1];  // [B,C,H,W]
    float* out = (float*)d_out;

    const size_t BHW = (size_t)BB * HWPX;
    // fpk (33.5 MB) | TN (4.2 MB) | partial (1.4 MB) | numer | denom   (~39 MB)
    float4* fpk     = (float4*)d_ws;
    float2* TN      = (float2*)((char*)d_ws + BHW * 64);
    float*  partial = (float*)((char*)TN + BHW * 8);
    float*  numer   = partial + (size_t)2 * KK * NT;
    float*  denom   = numer + BB * KK;

    prep<<<dim3((BB * HWPX) / 256), dim3(256), 0, stream>>>(cls, feat, fpk, TN);
    affinity_mfma<<<dim3(NT), dim3(256), 0, stream>>>(fpk, TN, cls, partial);
    reduce_part<<<dim3(2 * KK, BB), dim3(256), 0, stream>>>(partial, numer, denom);
    finalize<<<dim3(1), dim3(256), 0, stream>>>(numer, denom, out);
}

// Round 6
// 178.979 us; speedup vs baseline: 1.1555x; 1.1164x over previous
//
#include <hip/hip_runtime.h>

#define HH 256
#define WW 256
#define HWPX 65536
#define BB 8
#define KK 21
#define CC 32
#define NT 8192                 // affinity blocks
#define E_LOG2E 1.4426950408889634f
#define PEN -30000.0f           // exp2(PEN + bounded dot) flushes to exactly +0

typedef _Float16 half2v __attribute__((ext_vector_type(2)));
typedef _Float16 half8  __attribute__((ext_vector_type(8)));
typedef float    f32x4v __attribute__((ext_vector_type(4)));
union F4H { float4 f4; half2v h[4]; half8 h8; };

// ---------------- kernel 1: T + |q|^2 + planar f16 pack, 1 px/thread (verbatim, known-good) ----------------
__global__ __launch_bounds__(256) void prep(const float* __restrict__ cls,
                                            const float* __restrict__ feat,
                                            float4* __restrict__ fpk,
                                            float2* __restrict__ TN) {
    const int tid = blockIdx.x * 256 + threadIdx.x;   // 0..524287 (b*HWPX+p)
    const int b = tid >> 16;
    const int p = tid & (HWPX - 1);

    const float* cbase = cls + (size_t)b * KK * HWPX + p;
    float T = 0.f;
#pragma unroll
    for (int k = 0; k < KK; ++k) T += cbase[(size_t)k * HWPX];

    const float* src = feat + (size_t)b * CC * HWPX + p;
    float nq = 0.f;
#pragma unroll
    for (int j = 0; j < 4; ++j) {
        F4H u;
#pragma unroll
        for (int k = 0; k < 4; ++k) {
            float a  = src[(size_t)(j * 8 + 2 * k) * HWPX];
            float b2 = src[(size_t)(j * 8 + 2 * k + 1) * HWPX];
            u.h[k] = __builtin_bit_cast(half2v, __builtin_amdgcn_cvt_pkrtz(a, b2));
            nq = __builtin_amdgcn_fdot2(u.h[k], u.h[k], nq, false);
        }
        fpk[(size_t)j * (BB * HWPX) + tid] = u.f4;
    }
    TN[tid] = make_float2(T, nq);
}

// ---------------- kernel 2 (hot): MFMA affinity, 2x8 A-tile (10 windows, was 18) ----------------
// Wave owns a 2-row x 8-col px tile (16 px). A/C px mapping m <-> (ry=m&1, rx=m>>1) makes
// ry compile-time per C-reg (r&1). One 16-col B window [x0-4 .. x0+11] covers the dx span of
// ALL tile px exactly; ny in [y0-4, y0+5] -> 10 windows (valid-pair efficiency 43%, was 24%).
// dy^2 + circle mask folded into 5 static cst arrays (dy2 = 0/1/4/9/16); invalid -> PEN so
// exp2 flushes to +0. Windows dyi=0/9 touch only even/odd regs. All indexing compile-time.
__global__ __launch_bounds__(256) void affinity_mfma(const float4* __restrict__ fpk,
                                                     const float2* __restrict__ TN,
                                                     const float* __restrict__ cls,
                                                     float* __restrict__ partial) {
    __shared__ float smN[4][21], smD[4][21];
    const int L    = blockIdx.x;        // 0..8191 ; L%8 = batch (XCD swizzle)
    const int b    = L & 7;
    const int t    = L >> 3;            // 0..1023
    const int wid  = threadIdx.x >> 6;
    const int lane = threadIdx.x & 63;
    const int g    = lane >> 4;         // k-chunk = feature plane
    const int c    = lane & 15;         // fragment col
    const int idx  = t * 4 + wid;       // tile id 0..4095
    const int y0   = (idx >> 5) * 2;    // tile rows y0, y0+1
    const int x0   = (idx & 31) * 8;    // tile cols x0..x0+7

    const size_t bofs = (size_t)b * HWPX;
    const float4* fb  = fpk + bofs;
    const float2* tnb = TN + bofs;

    // A fragment: A-px m = c -> image px (y0 + (c&1), x0 + (c>>1)), channels 8g..8g+7
    F4H afr;
    afr.f4 = fb[(size_t)g * (BB * HWPX) + ((y0 + (c & 1)) << 8) + x0 + (c >> 1)];

    // own-px indices for my 4 C-rows: m = 4g+r -> (ry=r&1, rx=2g+(r>>1))
    int pxr[4];
    float npE[4];
#pragma unroll
    for (int r = 0; r < 4; ++r) {
        pxr[r] = ((y0 + (r & 1)) << 8) + x0 + 2 * g + (r >> 1);
        npE[r] = tnb[pxr[r]].y * E_LOG2E;
    }

    // B window x = x0-4+c ; per-lane loop-invariant byte offsets + validity
    const int xbu  = x0 - 4 + c;
    const bool inb = (unsigned)xbu < WW;
    const int xbc  = min(max(xbu, 0), WW - 1);
    const int voffF = (g * (BB * HWPX) + xbc) * 16;
    const int voffT = xbc * 8;

    // 5 static cst arrays: cstD[r] = -E/16*(dx2+D) - E*np[r], PEN if x-OOB or dx2 > lim(D)
    // lim: D<=4 -> dx2<=16 ; D=9 -> dx2<=9 ; D=16 -> dx2<=4   (dx2+D < 25)
    float cst0[4], cst1[4], cst4[4], cst9[4], cst16[4];
#pragma unroll
    for (int r = 0; r < 4; ++r) {
        const int dx = c - 4 - 2 * g - (r >> 1);
        const int s2 = dx * dx;
        cst0[r]  = (inb && s2 <= 16) ? fmaf((float)(s2 + 0),  -E_LOG2E / 16.f, -npE[r]) : PEN;
        cst1[r]  = (inb && s2 <= 16) ? fmaf((float)(s2 + 1),  -E_LOG2E / 16.f, -npE[r]) : PEN;
        cst4[r]  = (inb && s2 <= 16) ? fmaf((float)(s2 + 4),  -E_LOG2E / 16.f, -npE[r]) : PEN;
        cst9[r]  = (inb && s2 <= 9)  ? fmaf((float)(s2 + 9),  -E_LOG2E / 16.f, -npE[r]) : PEN;
        cst16[r] = (inb && s2 <= 4)  ? fmaf((float)(s2 + 16), -E_LOG2E / 16.f, -npE[r]) : PEN;
    }

    const f32x4v czero = {0.f, 0.f, 0.f, 0.f};
    float pdeg[4] = {0.f, 0.f, 0.f, 0.f};
    float pV[4]   = {0.f, 0.f, 0.f, 0.f};

    const char* fpkB = (const char*)fpk + bofs * 16;   // plane-0, batch b (bytes)
    const char* tnB  = (const char*)TN + bofs * 8;

    // mode: 0 = all regs, 1 = even regs only (dyi=0), 2 = odd regs only (dyi=9)
    auto body = [&](int ny, const float (&ce)[4], const float (&co)[4], int mode) {
        if ((unsigned)ny >= HH) return;                // wave-uniform OOB row
        const char* pF = fpkB + ((size_t)ny << 12);
        const char* pT = tnB  + ((size_t)ny << 11);
        F4H bfr; bfr.f4 = *(const float4*)(pF + voffF);
        const float2 tq = *(const float2*)(pT + voffT);
        f32x4v cz = __builtin_amdgcn_mfma_f32_16x16x32_f16(afr.h8, bfr.h8, czero, 0, 0, 0);
        const float t1 = tq.y * -E_LOG2E;
        if (mode != 2) {
            const float e0 = fmaf(cz[0], 2.f * E_LOG2E, ce[0] + t1);
            const float w0 = __builtin_exp2f(e0);
            pdeg[0] += w0;  pV[0] = fmaf(w0, tq.x, pV[0]);
            const float e2 = fmaf(cz[2], 2.f * E_LOG2E, ce[2] + t1);
            const float w2 = __builtin_exp2f(e2);
            pdeg[2] += w2;  pV[2] = fmaf(w2, tq.x, pV[2]);
        }
        if (mode != 1) {
            const float e1 = fmaf(cz[1], 2.f * E_LOG2E, co[1] + t1);
            const float w1 = __builtin_exp2f(e1);
            pdeg[1] += w1;  pV[1] = fmaf(w1, tq.x, pV[1]);
            const float e3 = fmaf(cz[3], 2.f * E_LOG2E, co[3] + t1);
            const float w3 = __builtin_exp2f(e3);
            pdeg[3] += w3;  pV[3] = fmaf(w3, tq.x, pV[3]);
        }
    };

    // dy(even regs) = dyi-4 ; dy(odd regs) = dyi-5
    body(y0 - 4, cst16, cst16, 1);
    body(y0 - 3, cst9,  cst16, 0);
    body(y0 - 2, cst4,  cst9,  0);
    body(y0 - 1, cst1,  cst4,  0);
    body(y0 + 0, cst0,  cst1,  0);
    body(y0 + 1, cst1,  cst0,  0);
    body(y0 + 2, cst4,  cst1,  0);
    body(y0 + 3, cst9,  cst4,  0);
    body(y0 + 4, cst16, cst9,  0);
    body(y0 + 5, cst16, cst16, 2);

    // col-sum over the 16 B cols (butterfly within 16-lane group)
#pragma unroll
    for (int m = 1; m <= 8; m <<= 1) {
#pragma unroll
        for (int r = 0; r < 4; ++r) {
            pdeg[r] += __shfl_xor(pdeg[r], m, 64);
            pV[r]   += __shfl_xor(pV[r], m, 64);
        }
    }

    // fused cls reduce: lane c handles j=c (and j=c+16 for c<5) over its 4 own px
    float n0 = 0.f, d0 = 0.f, n1 = 0.f, d1 = 0.f;
    const float* clsb = cls + (size_t)b * KK * HWPX;
#pragma unroll
    for (int r = 0; r < 4; ++r) {
        const float s0 = clsb[(size_t)c * HWPX + pxr[r]];
        n0 = fmaf(s0, pV[r], n0);
        d0 = fmaf(s0, pdeg[r], d0);
        if (c < 5) {
            const float s1 = clsb[(size_t)(c + 16) * HWPX + pxr[r]];
            n1 = fmaf(s1, pV[r], n1);
            d1 = fmaf(s1, pdeg[r], d1);
        }
    }
#pragma unroll
    for (int m = 16; m <= 32; m <<= 1) {
        n0 += __shfl_xor(n0, m, 64);
        d0 += __shfl_xor(d0, m, 64);
        n1 += __shfl_xor(n1, m, 64);
        d1 += __shfl_xor(d1, m, 64);
    }
    if (lane < 16) {
        smN[wid][lane] = n0;
        smD[wid][lane] = d0;
        if (lane < 5) { smN[wid][16 + lane] = n1; smD[wid][16 + lane] = d1; }
    }
    __syncthreads();
    if (threadIdx.x < 2 * KK) {                      // 42 partial slots per block, no atomics
        const int jq = threadIdx.x;
        const float v = (jq < KK)
            ? (smN[0][jq] + smN[1][jq] + smN[2][jq] + smN[3][jq])
            : (smD[0][jq - KK] + smD[1][jq - KK] + smD[2][jq - KK] + smD[3][jq - KK]);
        partial[(size_t)jq * NT + (size_t)b * 1024 + t] = v;
    }
}

// ---------------- kernel 3: sum per-block partials -> numer/denom[b][j] ----------------
__global__ __launch_bounds__(256) void reduce_part(const float* __restrict__ partial,
                                                   float* __restrict__ numer,
                                                   float* __restrict__ denom) {
    __shared__ float sm[4];
    const int jq = blockIdx.x;   // 0..41
    const int b  = blockIdx.y;   // 0..7
    const float* src = partial + (size_t)jq * NT + (size_t)b * 1024;
    float a = src[threadIdx.x] + src[threadIdx.x + 256]
            + src[threadIdx.x + 512] + src[threadIdx.x + 768];
#pragma unroll
    for (int off = 32; off > 0; off >>= 1) a += __shfl_down(a, off);
    if ((threadIdx.x & 63) == 0) sm[threadIdx.x >> 6] = a;
    __syncthreads();
    if (threadIdx.x == 0) {
        const float v = sm[0] + sm[1] + sm[2] + sm[3];
        if (jq < KK) numer[b * KK + jq] = v;
        else         denom[b * KK + jq - KK] = v;
    }
}

// ---------------- kernel 4: out = sum_{b,j} numer/denom ----------------
__global__ __launch_bounds__(256) void finalize(const float* __restrict__ numer,
                                                const float* __restrict__ denom,
                                                float* __restrict__ out) {
    __shared__ float sm[4];
    int i = threadIdx.x;
    float r = 0.f;
    if (i < BB * KK) r = numer[i] / denom[i];
#pragma unroll
    for (int off = 32; off > 0; off >>= 1) r += __shfl_down(r, off);
    if ((i & 63) == 0) sm[i >> 6] = r;
    __syncthreads();
    if (i == 0) out[0] = sm[0] + sm[1] + sm[2] + sm[3];
}

extern "C" void kernel_launch(void* const* d_in, const int* in_sizes, int n_in,
                              void* d_out, int out_size, void* d_ws, size_t ws_size,
                              hipStream_t stream) {
    const float* cls  = (const float*)d_in[0];  // [B,K,H,W]
    const float* feat = (const float*)d_in[1];  // [B,C,H,W]
    float* out = (float*)d_out;

    const size_t BHW = (size_t)BB * HWPX;
    // fpk (33.5 MB) | TN (4.2 MB) | partial (1.4 MB) | numer | denom   (~39 MB)
    float4* fpk     = (float4*)d_ws;
    float2* TN      = (float2*)((char*)d_ws + BHW * 64);
    float*  partial = (float*)((char*)TN + BHW * 8);
    float*  numer   = partial + (size_t)2 * KK * NT;
    float*  denom   = numer + BB * KK;

    prep<<<dim3((BB * HWPX) / 256), dim3(256), 0, stream>>>(cls, feat, fpk, TN);
    affinity_mfma<<<dim3(NT), dim3(256), 0, stream>>>(fpk, TN, cls, partial);
    reduce_part<<<dim3(2 * KK, BB), dim3(256), 0, stream>>>(partial, numer, denom);
    finalize<<<dim3(1), dim3(256), 0, stream>>>(numer, denom, out);
}